// Round 7
// baseline (310.972 us; speedup 1.0000x reference)
//
#include <hip/hip_runtime.h>

// y[n,m,:] = x[n,m,:] @ W[l(m)] * (1/sqrt(128))
// x: [100000, 16, 128] f32   W: [4, 128, 128] f32   y: [100000, 16, 128] f32
//
// R6 post-mortem: m-fast grid confirmed page-locality theory (342->309us,
// 5.2 TB/s = 83% of the 6.29 TB/s mixed-stream copy ceiling). R5's depth
// regression was confounded (also shrank tiles 32->16 rows); R7 isolates
// depth alone: ring of THREE 32-row buffers (48KB, 3 blocks/CU), depth-2
// prefetch, everything else byte-identical to R6. In-block vmcnt stall
// (~900cy HBM - ~450cy comp) drops to ~0: wait targets loads issued 2 comps
// ago. Derived per-wave waits (order L0,L1,[W]L2,s0,[W]L3,s1,[W]s2,[W]s3):
// vmcnt 4, 8, 12, 8. Cost: 16->12 waves/CU; stall removal should win.
//
// Unchanged: 2-phase global_load_lds staging (width 16), rule #21 both-sides
// swizzle (pre-swizzled global source slot^=row&7, linear DMA dest, XOR on
// ds_read), W register-resident per wave, m-fast grid. MFMA: A=W-frag(d),
// B=x-frag(n), same k->(lanegroup,elem) map both sides (K-perm cancels).
// D: col(lane&15)=n, row((lane>>4)*4+reg)=d (HW-verified R1-R6).

typedef __bf16 bf16x8 __attribute__((ext_vector_type(8)));
typedef float f32x4 __attribute__((ext_vector_type(4)));
typedef unsigned short u16x8 __attribute__((ext_vector_type(8)));

#define N_NODES 100000
#define MCOMP 16
#define CIN 128
#define ROWSTRIDE (MCOMP * CIN)  // 2048 floats per node

__device__ __forceinline__ unsigned short f2b(float f) {
    unsigned int u = __float_as_uint(f);
    unsigned int r = (u + 0x7fffu + ((u >> 16) & 1u)) >> 16;
    return (unsigned short)r;
}

// Wt[l][d][c] = W[l][c][d] * (1/sqrt(128)) as bf16 bits. 128 KiB in d_ws.
__global__ void prep_weights(const float* __restrict__ w,
                             unsigned short* __restrict__ wt) {
    int idx = blockIdx.x * blockDim.x + threadIdx.x;  // 0..65535
    int l = idx >> 14;
    int rem = idx & 16383;
    int d = rem >> 7;
    int c = rem & 127;
    const float pw = 0.08838834764831845f;  // 1/sqrt(128)
    wt[idx] = f2b(w[(l << 14) + (c << 7) + d] * pw);
}

__global__ __launch_bounds__(256, 4) void linear_mfma(
        const float* __restrict__ x,
        const unsigned short* __restrict__ wt,
        float* __restrict__ y) {
    __shared__ float ldsb[3][32 * 128];  // ring of 3 x 16 KiB (48 KiB)

    const int m = blockIdx.x;          // FAST dispatch dim: all 16 m adjacent
    const int l = (m >= 9) ? 3 : (m >= 4) ? 2 : (m >= 1) ? 1 : 0;
    const int wid = threadIdx.x >> 6;
    const int lane = threadIdx.x & 63;
    const int lr = lane & 15;   // W-frag d-row / x-frag n / D col (n)
    const int lk = lane >> 4;   // k lane-group
    const int nbase = blockIdx.y * 128;

    // W fragments, register-resident: d = wid*32 + df*16 + lr, k = kk*32+lk*8..+8
    const unsigned short* wl = wt + (l << 14);
    bf16x8 wf[2][4];
#pragma unroll
    for (int df = 0; df < 2; ++df)
#pragma unroll
        for (int kk = 0; kk < 4; ++kk)
            wf[df][kk] = __builtin_bit_cast(bf16x8, *(const u16x8*)(
                wl + (((wid * 32 + df * 16 + lr) << 7) + kk * 32 + lk * 8)));

    // stage half h (rows nbase+h*32 .. +32) into buf: 4 global_load_lds/wave,
    // LDS linear; global source pre-swizzled slot^=(row&7).
    auto stage = [&](float* buf, int h) {
        const int hbase = nbase + h * 32;
#pragma unroll
        for (int j = 0; j < 4; ++j) {
            int seg = wid * 4 + j;                 // 1KB segment, wave-uniform
            int row = seg * 2 + (lane >> 5);       // 2 rows per segment
            int slot = (lane & 31) ^ (row & 7);    // 16B slot, pre-swizzled
            const float* src = x + (size_t)(hbase + row) * ROWSTRIDE
                               + m * CIN + slot * 4;
            __builtin_amdgcn_global_load_lds(
                (const __attribute__((address_space(1))) void*)src,
                (__attribute__((address_space(3))) void*)(buf + seg * 256),
                16, 0, 0);
        }
    };

    // compute half h from buf (ds_read XOR-deswizzled), MFMA, store to y.
    // Exactly 4 vmem stores per wave (counted in the vmcnt discipline).
    auto comp = [&](const float* buf, int h) {
        f32x4 acc[2][2];
#pragma unroll
        for (int rf = 0; rf < 2; ++rf)
#pragma unroll
            for (int df = 0; df < 2; ++df)
                acc[rf][df] = (f32x4){0.f, 0.f, 0.f, 0.f};

#pragma unroll
        for (int kk = 0; kk < 4; ++kk) {
#pragma unroll
            for (int rf = 0; rf < 2; ++rf) {
                int row = rf * 16 + lr;
                int sw = row & 7;
                const float* rbase = buf + row * 128 + kk * 32;
                f32x4 v0 = *(const f32x4*)(rbase + ((lk * 2) ^ sw) * 4);
                f32x4 v1 = *(const f32x4*)(rbase + ((lk * 2 + 1) ^ sw) * 4);
                bf16x8 xb;
#pragma unroll
                for (int jj = 0; jj < 4; ++jj) {
                    xb[jj] = (__bf16)v0[jj];
                    xb[jj + 4] = (__bf16)v1[jj];
                }
                acc[rf][0] = __builtin_amdgcn_mfma_f32_16x16x32_bf16(
                    wf[0][kk], xb, acc[rf][0], 0, 0, 0);
                acc[rf][1] = __builtin_amdgcn_mfma_f32_16x16x32_bf16(
                    wf[1][kk], xb, acc[rf][1], 0, 0, 0);
            }
        }
        const int hbase = nbase + h * 32;
#pragma unroll
        for (int rf = 0; rf < 2; ++rf)
#pragma unroll
            for (int df = 0; df < 2; ++df) {
                float* yp = y + (size_t)(hbase + rf * 16 + lr) * ROWSTRIDE
                            + m * CIN + wid * 32 + df * 16 + lk * 4;
                *(f32x4*)yp = acc[rf][df];
            }
    };

    if (nbase + 128 <= N_NODES) {
        // depth-2 schedule over 4 tiles, ring b0,b1,b2:
        stage(ldsb[0], 0);
        stage(ldsb[1], 1);

        asm volatile("s_waitcnt vmcnt(4)" ::: "memory");   // L0 landed
        __builtin_amdgcn_s_barrier();
        stage(ldsb[2], 2);
        __builtin_amdgcn_sched_barrier(0);
        comp(ldsb[0], 0);

        asm volatile("s_waitcnt vmcnt(8)" ::: "memory");   // L1 landed (L2+s0 out)
        __builtin_amdgcn_s_barrier();
        stage(ldsb[0], 3);
        __builtin_amdgcn_sched_barrier(0);
        comp(ldsb[1], 1);

        asm volatile("s_waitcnt vmcnt(12)" ::: "memory");  // L2 landed (s0+L3+s1 out)
        __builtin_amdgcn_s_barrier();
        __builtin_amdgcn_sched_barrier(0);
        comp(ldsb[2], 2);

        asm volatile("s_waitcnt vmcnt(8)" ::: "memory");   // L3 landed (s1+s2 out)
        __builtin_amdgcn_s_barrier();
        __builtin_amdgcn_sched_barrier(0);
        comp(ldsb[0], 3);
    } else {
        // tail block: exactly 32 rows (100000 % 128 == 32), one tile
        stage(ldsb[0], 0);
        asm volatile("s_waitcnt vmcnt(0)" ::: "memory");
        __builtin_amdgcn_s_barrier();
        comp(ldsb[0], 0);
    }
}

extern "C" void kernel_launch(void* const* d_in, const int* in_sizes, int n_in,
                              void* d_out, int out_size, void* d_ws, size_t ws_size,
                              hipStream_t stream) {
    const float* x = (const float*)d_in[0];
    const float* w = (const float*)d_in[1];
    float* y = (float*)d_out;
    unsigned short* wt = (unsigned short*)d_ws;  // 128 KiB of scratch used

    prep_weights<<<256, 256, 0, stream>>>(w, wt);

    // m fast, node-tile slow (R6 win): one sequential HBM sweep.
    dim3 grid(MCOMP, (N_NODES + 127) / 128);  // 16 x 782
    linear_mfma<<<grid, 256, 0, stream>>>(x, wt, y);
}